// Round 19
// baseline (4534.436 us; speedup 1.0000x reference)
//
#include <hip/hip_runtime.h>
#include <stdint.h>

// ---------------------------------------------------------------------------
// 2-layer LSTM (B=64,T=128,NA=2048,H=1024) + softmax head, bf16 MFMA.
//   per 32-step chunk: Z0c = Xc @ W0x (bf16x3 MFMA GEMM) then ONE persistent
//   segment running 32 pipelined iterations (L0(t) || L1(t-1)).
// R19 = R18 (best, 3995us) + micro-bundle:
//   (1) drain iteration folded into segment 4 (t1=129): one fewer launch +
//       weight restage; (2) pass-0 A-loads + Z0c issued BEFORE zbuf-zero sync
//       (off the critical path); (3) s_sleep(1) barrier polls (faster flag
//       observation). Structure otherwise identical: 256 WGs x 512 thr,
//   16 units x 32 batches per WG (24 MB/iter broadcast), W single-bf16 in
//   VGPRs (wh[4][8]), blocked h/hs, sc0sc1 A-loads + vmcnt(0) per pass,
//   light 2-hop barrier, sc1 stores, c-state in VGPRs.
// ---------------------------------------------------------------------------

typedef __attribute__((ext_vector_type(4))) float f32x4;
typedef __attribute__((ext_vector_type(8))) short short8x;
typedef unsigned short ushort_t;

constexpr int B_  = 64;
constexpr int T_  = 128;
constexpr int NA_ = 2048;
constexpr int H_  = 1024;
constexpr int C_  = 10;
constexpr int BT_ = B_ * T_;     // 8192
constexpr int G4_ = 4 * H_;      // 4096
constexpr int HB_ = B_ * H_;     // 65536 ushorts per parity (blocked 128x64x8)
constexpr int CH_ = 32;          // timesteps per chunk
constexpr int MC_ = B_ * CH_;    // 2048 rows per chunk
constexpr int NWGP_ = 256;       // persistent grid, 1 WG/CU

__device__ __forceinline__ ushort_t f2bf(float x) {
    uint32_t u = __float_as_uint(x);
    uint32_t r = (u + 0x7FFFu + ((u >> 16) & 1u)) >> 16;   // RNE
    return (ushort_t)r;
}
__device__ __forceinline__ float bf2f(ushort_t h) {
    return __uint_as_float((uint32_t)h << 16);
}
__device__ __forceinline__ float sigmf(float x) { return 1.0f / (1.0f + expf(-x)); }

__device__ __forceinline__ void st_u32(void* p, uint32_t v) {
    __hip_atomic_store((uint32_t*)p, v, __ATOMIC_RELAXED, __HIP_MEMORY_SCOPE_AGENT);
}

// Coalesced read-through 16B load (reads coherence point; needs vmcnt fence)
#define AH_ISSUE(dst, ptr) \
    asm volatile("global_load_dwordx4 %0, %1, off sc0 sc1" : "=v"(dst) : "v"(ptr))

#define GLOAD_LDS(gp, lp) \
    __builtin_amdgcn_global_load_lds((const __attribute__((address_space(1))) uint32_t*)(gp), \
                                     (__attribute__((address_space(3))) uint32_t*)(lp), 16, 0, 0)

// ---------------------------------------------------------------------------
// X chunk c -> (hi, lo) decompose with row remap m' = b*CH + (t & 31)
// ---------------------------------------------------------------------------
__global__ void decomp_chunk(const float* __restrict__ X, int c,
                             ushort_t* __restrict__ Hi, ushort_t* __restrict__ Lo) {
    const int i = blockIdx.x * blockDim.x + threadIdx.x;
    if (i >= MC_ * NA_ / 4) return;
    const int mp = i >> 9;
    const int kq = i & 511;
    const int b = mp >> 5, j = mp & 31;
    const size_t src = ((size_t)(b * T_ + c * CH_ + j)) * NA_ + (size_t)kq * 4;
    float4 v = *(const float4*)(X + src);
    ushort4 hi, lo;
    hi.x = f2bf(v.x); lo.x = f2bf(v.x - bf2f(hi.x));
    hi.y = f2bf(v.y); lo.y = f2bf(v.y - bf2f(hi.y));
    hi.z = f2bf(v.z); lo.z = f2bf(v.z - bf2f(hi.z));
    hi.w = f2bf(v.w); lo.w = f2bf(v.w - bf2f(hi.w));
    ((ushort4*)Hi)[i] = hi;
    ((ushort4*)Lo)[i] = lo;
}

// ---------------------------------------------------------------------------
// W -> T{hi,lo}[n][k] bf16 transpose (input-projection GEMM operands)
// ---------------------------------------------------------------------------
__global__ void transdec(const float* __restrict__ W, int rowOff, int Klen,
                         ushort_t* __restrict__ Thi, ushort_t* __restrict__ Tlo) {
    __shared__ float tile[32][33];
    const int k0 = blockIdx.x * 32, n0 = blockIdx.y * 32;
    const int tx = threadIdx.x & 31, ty = threadIdx.x >> 5;
#pragma unroll
    for (int i = 0; i < 32; i += 8)
        tile[ty + i][tx] = W[(size_t)(rowOff + k0 + ty + i) * G4_ + n0 + tx];
    __syncthreads();
#pragma unroll
    for (int i = 0; i < 32; i += 8) {
        float v = tile[tx][ty + i];
        int n = n0 + ty + i;
        int kk = k0 + tx;
        ushort_t hi = f2bf(v);
        Thi[(size_t)n * Klen + kk] = hi;
        Tlo[(size_t)n * Klen + kk] = f2bf(v - bf2f(hi));
    }
}

// ---------------------------------------------------------------------------
// W -> T[n][k] bf16 transpose, hi only (recurrent weights, single-bf16)
// ---------------------------------------------------------------------------
__global__ void transb(const float* __restrict__ W, int rowOff, int Klen,
                       ushort_t* __restrict__ Tq) {
    __shared__ float tile[32][33];
    const int k0 = blockIdx.x * 32, n0 = blockIdx.y * 32;
    const int tx = threadIdx.x & 31, ty = threadIdx.x >> 5;
#pragma unroll
    for (int i = 0; i < 32; i += 8)
        tile[ty + i][tx] = W[(size_t)(rowOff + k0 + ty + i) * G4_ + n0 + tx];
    __syncthreads();
#pragma unroll
    for (int i = 0; i < 32; i += 8) {
        float v = tile[tx][ty + i];
        int n = n0 + ty + i;
        Tq[(size_t)n * Klen + k0 + tx] = f2bf(v);
    }
}

// ---------------------------------------------------------------------------
// C[M][N] (fp32) = A[M][K] x Bt[N][K]^T  bf16x3; m97-style 128x128 tile.
// ---------------------------------------------------------------------------
__global__ __launch_bounds__(256, 2)
void gemm_bf16x3(const ushort_t* __restrict__ Ahi, const ushort_t* __restrict__ Alo,
                 const ushort_t* __restrict__ Bhi, const ushort_t* __restrict__ Blo,
                 float* __restrict__ C, int M, int N, int K) {
    __shared__ ushort_t sA[2][128 * 64];
    __shared__ ushort_t sB[2][128 * 64];

    const int tid  = threadIdx.x;
    const int lane = tid & 63;
    const int wv   = tid >> 6;
    const int wr   = wv >> 1, wc = wv & 1;
    const int tiles_n = N >> 7;
    int id = blockIdx.x;
    const int q8 = gridDim.x >> 3;
    id = (id & 7) * q8 + (id >> 3);
    const int tm = (id / tiles_n) * 128, tn = (id % tiles_n) * 128;

    f32x4 acc[4][4] = {};

    for (int k0 = 0; k0 < K; k0 += 64) {
#pragma unroll
        for (int rd = 0; rd < 4; ++rd) {
            const int off = rd * 4096 + tid * 16;
            const int r   = off >> 7;
            const int kc  = ((off >> 4) & 7) ^ (r & 7);
            const size_t aoff = (size_t)(tm + r) * K + k0 + kc * 8;
            const size_t boff = (size_t)(tn + r) * K + k0 + kc * 8;
            const int dst = (rd * 4096 + wv * 1024) >> 1;
            GLOAD_LDS(Ahi + aoff, (ushort_t*)sA[0] + dst);
            GLOAD_LDS(Alo + aoff, (ushort_t*)sA[1] + dst);
            GLOAD_LDS(Bhi + boff, (ushort_t*)sB[0] + dst);
            GLOAD_LDS(Blo + boff, (ushort_t*)sB[1] + dst);
        }
        __syncthreads();
#pragma unroll
        for (int ks = 0; ks < 2; ++ks) {
            short8x ah[4], al[4], bh[4], bl[4];
#pragma unroll
            for (int i = 0; i < 4; ++i) {
                const int kc = ks * 4 + (lane >> 4);
                const int ra = wr * 64 + i * 16 + (lane & 15);
                const int ea = ra * 64 + ((kc ^ (ra & 7)) * 8);
                ah[i] = *(const short8x*)(&sA[0][ea]);
                al[i] = *(const short8x*)(&sA[1][ea]);
                const int rb = wc * 64 + i * 16 + (lane & 15);
                const int eb = rb * 64 + ((kc ^ (rb & 7)) * 8);
                bh[i] = *(const short8x*)(&sB[0][eb]);
                bl[i] = *(const short8x*)(&sB[1][eb]);
            }
#pragma unroll
            for (int i = 0; i < 4; ++i)
#pragma unroll
                for (int j = 0; j < 4; ++j) {
                    acc[i][j] = __builtin_amdgcn_mfma_f32_16x16x32_bf16(ah[i], bh[j], acc[i][j], 0, 0, 0);
                    acc[i][j] = __builtin_amdgcn_mfma_f32_16x16x32_bf16(ah[i], bl[j], acc[i][j], 0, 0, 0);
                    acc[i][j] = __builtin_amdgcn_mfma_f32_16x16x32_bf16(al[i], bh[j], acc[i][j], 0, 0, 0);
                }
        }
        __syncthreads();
    }
#pragma unroll
    for (int i = 0; i < 4; ++i)
#pragma unroll
        for (int j = 0; j < 4; ++j)
#pragma unroll
            for (int qq = 0; qq < 4; ++qq) {
                const int row = tm + wr * 64 + i * 16 + (lane >> 4) * 4 + qq;
                const int col = tn + wc * 64 + j * 16 + (lane & 15);
                C[(size_t)row * N + col] = acc[i][j][qq];
            }
}

// ---------------------------------------------------------------------------
// Light two-hop grid barrier; s_sleep(1) polls for fast flag observation.
// ---------------------------------------------------------------------------
__device__ __forceinline__ void grid_bar(unsigned* slots, unsigned* flag, unsigned epoch) {
    __syncthreads();   // drains vmcnt: this WG's sc1 stores are globally visible
    if (threadIdx.x == 0)
        __hip_atomic_store(&slots[blockIdx.x], epoch, __ATOMIC_RELAXED, __HIP_MEMORY_SCOPE_AGENT);
    if (blockIdx.x == 0) {
        if (threadIdx.x < NWGP_) {
            unsigned spins = 0;
            while (__hip_atomic_load(&slots[threadIdx.x], __ATOMIC_RELAXED, __HIP_MEMORY_SCOPE_AGENT) < epoch
                   && ++spins < (1u << 22))
                __builtin_amdgcn_s_sleep(1);
        }
        __syncthreads();
        if (threadIdx.x == 0)
            __hip_atomic_store(flag, epoch, __ATOMIC_RELAXED, __HIP_MEMORY_SCOPE_AGENT);
    } else {
        if (threadIdx.x == 0) {
            unsigned spins = 0;
            while (__hip_atomic_load(flag, __ATOMIC_RELAXED, __HIP_MEMORY_SCOPE_AGENT) < epoch
                   && ++spins < (1u << 22))
                __builtin_amdgcn_s_sleep(1);
        }
    }
    __syncthreads();
}

// ---------------------------------------------------------------------------
// Persistent recurrence SEGMENT. 256 WGs x 512 thr (1 WG/CU).
// WG w<128: L0; else L1. lw = w mod 128: uB16 = lw>>1 (16-unit block 0..63),
// mh = lw&1 (batch half: m0 = mh*32). N=64 gate-rows/WG, M=32 batches/WG.
// 8 waves K-split (KS 128/256, NKS 4/8 -> npass 2/4). W in VGPRs wh[4][8].
// h blocked [parity][kblock(128)][batch(64)][8]; A-frag = one 16B read.
// Pass-0 loads + Z0c issued BEFORE the zbuf-zero sync (early-issue).
// c-state in VGPRs across the segment. LDS = zbuf only.
// ---------------------------------------------------------------------------
__global__ __launch_bounds__(512, 1)
void lstm_persist(int t0, int t1,
                  const float* __restrict__ Z0c,
                  const ushort_t* __restrict__ W0hT, const ushort_t* __restrict__ W1T,
                  const float* __restrict__ b0, const float* __restrict__ b1,
                  ushort_t* __restrict__ h0blk, ushort_t* __restrict__ h1blk,
                  float* __restrict__ c0, float* __restrict__ c1,
                  ushort_t* __restrict__ hsblk, unsigned* slots, unsigned* flag) {
    const int w = blockIdx.x;
    const bool isL0 = (w < 128);
    const int lw = isL0 ? w : (w - 128);
    const int uB16 = lw >> 1;          // 16-unit block 0..63
    const int mh   = lw & 1;           // batch half
    const int u0 = uB16 * 16;
    const int m0 = mh * 32;
    const int tid = threadIdx.x, lane = tid & 63, kv = tid >> 6;
    const int K   = isL0 ? H_ : 2 * H_;
    const int KS  = K >> 3;            // 128 / 256
    const int NKS = KS >> 5;           // 4 / 8
    const int kbase = kv * KS;

    __shared__ float zbuf[32][65];     // 8.3 KB — only LDS use

    // --- startup: weights (single bf16) -> VGPRs, fragment layout ---
    const ushort_t* Whi = isL0 ? W0hT : W1T;
    short8x wh[4][8] = {};
#pragma unroll
    for (int jn = 0; jn < 4; ++jn)
#pragma unroll
        for (int s = 0; s < 8; ++s)
            if (s < NKS) {
                const int n = jn * 16 + (lane & 15);
                const int grow = (n >> 4) * H_ + u0 + (n & 15);
                wh[jn][s] = *(const short8x*)(Whi + (size_t)grow * K + kbase + s * 32 + (lane >> 4) * 8);
            }

    // epilogue mapping: threads 0..255, each (local batch ml, unit pair jp,jp+1)
    const bool epi = (tid < 256);
    const int ml = tid >> 3;           // 0..31
    const int em = m0 + ml;            // global batch
    const int jp = (tid & 7) * 2;      // 0..14
    const int eu = u0 + jp;
    const float* bias = isL0 ? b0 : b1;
    const float bi0 = epi ? bias[eu]            : 0.f, bi1 = epi ? bias[eu + 1]            : 0.f;
    const float bj0 = epi ? bias[H_ + eu]       : 0.f, bj1 = epi ? bias[H_ + eu + 1]       : 0.f;
    const float bf0 = epi ? bias[2 * H_ + eu]   : 0.f, bf1 = epi ? bias[2 * H_ + eu + 1]   : 0.f;
    const float bo0 = epi ? bias[3 * H_ + eu]   : 0.f, bo1 = epi ? bias[3 * H_ + eu + 1]   : 0.f;
    const int zm = tid >> 4, zj = (tid & 15) * 4;   // zbuf zero map (512 thr x 4)

    // c-state resident in VGPRs for the segment
    float cr0 = 0.f, cr1 = 0.f;
    float* cptr = (isL0 ? c0 : c1) + (size_t)em * H_ + eu;
    if (epi) { float2 cv = *(const float2*)cptr; cr0 = cv.x; cr1 = cv.y; }

    for (int t = t0; t < t1; ++t) {
        const bool active = isL0 ? (t < T_) : (t >= 1);
        if (active) {
            const int tt = isL0 ? t : t - 1;
            const ushort_t* h0prev = h0blk + ((tt + 1) & 1) * HB_;
            const ushort_t* h0cur  = h0blk + (tt & 1) * HB_;
            const ushort_t* h1prev = h1blk + ((tt + 1) & 1) * HB_;

            f32x4 acc[2][4] = {};
            short8x ah[2][2];                 // 4 x 16B live = 16 VGPRs
            const int npass = NKS >> 1;       // 2 for L0, 4 for L1

            // ---- EARLY ISSUE: pass-0 A-loads + Z0c, before the zbuf sync ----
#pragma unroll
            for (int s2 = 0; s2 < 2; ++s2) {
                const int kg = kbase + s2 * 32;
                const ushort_t* base;
                int kk;
                if (isL0)           { base = h0prev; kk = kg; }
                else if (kg < 1024) { base = h0cur;  kk = kg; }
                else                { base = h1prev; kk = kg - 1024; }
                const int kaa = kk + (lane >> 4) * 8;
#pragma unroll
                for (int i = 0; i < 2; ++i) {
                    const int batch = m0 + i * 16 + (lane & 15);
                    AH_ISSUE(ah[s2][i], base + (size_t)(kaa >> 3) * 512 + (size_t)batch * 8);
                }
            }
            float2 zx0 = {0.f, 0.f}, zx1 = {0.f, 0.f}, zx2 = {0.f, 0.f}, zx3 = {0.f, 0.f};
            if (isL0 && epi) {
                const float* zr = Z0c + ((size_t)em * CH_ + (tt & (CH_ - 1))) * G4_;
                zx0 = *(const float2*)(zr + eu);
                zx1 = *(const float2*)(zr + H_ + eu);
                zx2 = *(const float2*)(zr + 2 * H_ + eu);
                zx3 = *(const float2*)(zr + 3 * H_ + eu);
            }

            // zero gate-exchange cells (4 per thread: 512x4 = 32x64)
            zbuf[zm][zj] = 0.f; zbuf[zm][zj + 1] = 0.f;
            zbuf[zm][zj + 2] = 0.f; zbuf[zm][zj + 3] = 0.f;
            __syncthreads();

#pragma unroll
            for (int pp = 0; pp < 4; ++pp)
                if (pp < npass) {
                    asm volatile("s_waitcnt vmcnt(0)" ::: "memory");
                    __builtin_amdgcn_sched_barrier(0);
                    // MFMA on current buffer, then issue next pass's loads
                    short8x cur[2][2];
#pragma unroll
                    for (int s2 = 0; s2 < 2; ++s2)
#pragma unroll
                        for (int i = 0; i < 2; ++i) cur[s2][i] = ah[s2][i];
                    if (pp + 1 < npass) {
#pragma unroll
                        for (int s2 = 0; s2 < 2; ++s2) {
                            const int s = (pp + 1) * 2 + s2;
                            const int kg = kbase + s * 32;
                            const ushort_t* base;
                            int kk;
                            if (isL0)           { base = h0prev; kk = kg; }
                            else if (kg < 1024) { base = h0cur;  kk = kg; }
                            else                { base = h1prev; kk = kg - 1024; }
                            const int kaa = kk + (lane >> 4) * 8;
#pragma unroll
                            for (int i = 0; i < 2; ++i) {
                                const int batch = m0 + i * 16 + (lane & 15);
                                AH_ISSUE(ah[s2][i], base + (size_t)(kaa >> 3) * 512 + (size_t)batch * 8);
                            }
                        }
                    }
#pragma unroll
                    for (int s2 = 0; s2 < 2; ++s2) {
                        const int s = pp * 2 + s2;
#pragma unroll
                        for (int i = 0; i < 2; ++i) {
                            acc[i][0] = __builtin_amdgcn_mfma_f32_16x16x32_bf16(cur[s2][i], wh[0][s], acc[i][0], 0, 0, 0);
                            acc[i][1] = __builtin_amdgcn_mfma_f32_16x16x32_bf16(cur[s2][i], wh[1][s], acc[i][1], 0, 0, 0);
                            acc[i][2] = __builtin_amdgcn_mfma_f32_16x16x32_bf16(cur[s2][i], wh[2][s], acc[i][2], 0, 0, 0);
                            acc[i][3] = __builtin_amdgcn_mfma_f32_16x16x32_bf16(cur[s2][i], wh[3][s], acc[i][3], 0, 0, 0);
                        }
                    }
                }
            // K-reduction across 8 waves; per-wave rotated order
#pragma unroll
            for (int i2 = 0; i2 < 2; ++i2) {
                const int i = (i2 + (kv & 1)) & 1;
#pragma unroll
                for (int jn2 = 0; jn2 < 4; ++jn2) {
                    const int jn = (jn2 + (kv >> 1)) & 3;
#pragma unroll
                    for (int qq = 0; qq < 4; ++qq) {
                        const int m = i * 16 + (lane >> 4) * 4 + qq;     // local batch
                        const int n = jn * 16 + (lane & 15);             // gate-row
                        atomicAdd(&zbuf[m][n], acc[i][jn][qq]);
                    }
                }
            }
            __syncthreads();

            // epilogue: threads 0..255; gate-row n = g*16 + unit
            if (epi) {
                const float zi0 = zbuf[ml][jp]          + bi0 + zx0.x;
                const float zi1 = zbuf[ml][jp + 1]      + bi1 + zx0.y;
                const float zj0 = zbuf[ml][16 + jp]     + bj0 + zx1.x;
                const float zj1 = zbuf[ml][16 + jp + 1] + bj1 + zx1.y;
                const float zf0 = zbuf[ml][32 + jp]     + bf0 + zx2.x;
                const float zf1 = zbuf[ml][32 + jp + 1] + bf1 + zx2.y;
                const float zo0 = zbuf[ml][48 + jp]     + bo0 + zx3.x;
                const float zo1 = zbuf[ml][48 + jp + 1] + bo1 + zx3.y;
                const float cn0 = cr0 * sigmf(zf0 + 1.0f) + sigmf(zi0) * tanhf(zj0);
                const float cn1 = cr1 * sigmf(zf1 + 1.0f) + sigmf(zi1) * tanhf(zj1);
                cr0 = cn0; cr1 = cn1;
                const float hv0 = tanhf(cn0) * sigmf(zo0);
                const float hv1 = tanhf(cn1) * sigmf(zo1);
                const uint32_t hhp = (uint32_t)f2bf(hv0) | ((uint32_t)f2bf(hv1) << 16);
                const int kb = uB16 * 2 + (jp >> 3);       // 8-unit block
                const size_t hoff = ((size_t)kb * 64 + em) * 8 + (jp & 7);
                if (isL0) {
                    st_u32(h0blk + (tt & 1) * HB_ + hoff, hhp);
                } else {
                    st_u32(h1blk + (tt & 1) * HB_ + hoff, hhp);
                    st_u32(hsblk + (((size_t)tt * 128 + kb) * 64 + em) * 8 + (jp & 7), hhp);
                }
            }
        }
        if (t < T_) grid_bar(slots, flag, (unsigned)(t + 1));
    }

    // c-state back to global (plain; flushed at end-of-kernel)
    if (epi) { float2 cv; cv.x = cr0; cv.y = cr1; *(float2*)cptr = cv; }
}

// ---------------------------------------------------------------------------
// logits = hs @ Wout + bout; softmax over C=10. One wave per (b,t) row.
// hs blocked: hs[((t*128 + (k>>3))*512) + b*8 + (k&7)].
// ---------------------------------------------------------------------------
__global__ __launch_bounds__(256)
void out_softmax(const ushort_t* __restrict__ hs, const float* __restrict__ Wout,
                 const float* __restrict__ bout, float* __restrict__ out) {
    const int row  = blockIdx.x * 4 + (threadIdx.x >> 6);
    const int lane = threadIdx.x & 63;
    const int b = row >> 7, t = row & (T_ - 1);
    float s[C_];
#pragma unroll
    for (int c = 0; c < C_; ++c) s[c] = 0.f;
    for (int k = lane; k < H_; k += 64) {
        const float hv = bf2f(hs[((size_t)t * 128 + (k >> 3)) * 512 + (size_t)b * 8 + (k & 7)]);
        const float* w = Wout + k * C_;
#pragma unroll
        for (int c = 0; c < C_; ++c) s[c] += hv * w[c];
    }
#pragma unroll
    for (int c = 0; c < C_; ++c) {
#pragma unroll
        for (int d = 32; d > 0; d >>= 1) s[c] += __shfl_xor(s[c], d);
        s[c] += bout[c];
    }
    float mx = s[0];
#pragma unroll
    for (int c = 1; c < C_; ++c) mx = fmaxf(mx, s[c]);
    float sum = 0.f;
#pragma unroll
    for (int c = 0; c < C_; ++c) { s[c] = expf(s[c] - mx); sum += s[c]; }
    const float inv = 1.0f / sum;
    if (lane < C_) {
        float pv = 0.f;
#pragma unroll
        for (int c = 0; c < C_; ++c)
            if (lane == c) pv = s[c] * inv;
        out[(size_t)row * C_ + lane] = pv;
    }
}

// ---------------------------------------------------------------------------
extern "C" void kernel_launch(void* const* d_in, const int* in_sizes, int n_in,
                              void* d_out, int out_size, void* d_ws, size_t ws_size,
                              hipStream_t stream) {
    const float* X    = (const float*)d_in[0];
    const float* W0   = (const float*)d_in[1];
    const float* b0   = (const float*)d_in[2];
    const float* W1   = (const float*)d_in[3];
    const float* b1   = (const float*)d_in[4];
    const float* Wout = (const float*)d_in[5];
    const float* bout = (const float*)d_in[6];
    float* out = (float*)d_out;

    // ws layout (~121 MB)
    char* p = (char*)d_ws;
    size_t off = 0;
    auto take = [&](size_t bytes) { char* r = p + off; off += bytes; return r; };
    ushort_t* W0xT_hi = (ushort_t*)take((size_t)G4_ * NA_ * 2);     // 16 MB
    ushort_t* W0xT_lo = (ushort_t*)take((size_t)G4_ * NA_ * 2);     // 16 MB
    ushort_t* W0hT    = (ushort_t*)take((size_t)G4_ * H_ * 2);      // 8 MB
    ushort_t* W1T     = (ushort_t*)take((size_t)G4_ * 2 * H_ * 2);  // 16 MB
    ushort_t* Xc_hi   = (ushort_t*)take((size_t)MC_ * NA_ * 2);     // 8 MB
    ushort_t* Xc_lo   = (ushort_t*)take((size_t)MC_ * NA_ * 2);     // 8 MB
    float*    Z0c     = (float*)take((size_t)MC_ * G4_ * 4);        // 32 MB
    ushort_t* hsblk   = (ushort_t*)take((size_t)BT_ * H_ * 2);      // 16 MB
    float*    c0      = (float*)take((size_t)B_ * H_ * 4);
    float*    c1      = (float*)take((size_t)B_ * H_ * 4);
    ushort_t* h0blk   = (ushort_t*)take((size_t)2 * HB_ * 2);
    ushort_t* h1blk   = (ushort_t*)take((size_t)2 * HB_ * 2);
    unsigned* bar     = (unsigned*)take(2048);
    if (ws_size < off) return;

    unsigned* slots = bar;          // 256 x u32 per-WG arrival slots
    unsigned* flag  = bar + 256;    // release flag

    // zero-state init (parity-1 regions are the t=-1 reads); barrier = 0
    (void)hipMemsetAsync(c0, 0, (size_t)B_ * H_ * 4, stream);
    (void)hipMemsetAsync(c1, 0, (size_t)B_ * H_ * 4, stream);
    (void)hipMemsetAsync(h0blk + HB_, 0, (size_t)HB_ * 2, stream);
    (void)hipMemsetAsync(h1blk + HB_, 0, (size_t)HB_ * 2, stream);
    (void)hipMemsetAsync(bar, 0, 2048, stream);

    // weight prep
    transdec<<<dim3(NA_ / 32, G4_ / 32), 256, 0, stream>>>(W0, 0, NA_, W0xT_hi, W0xT_lo);
    transb  <<<dim3(H_ / 32, G4_ / 32), 256, 0, stream>>>(W0, NA_, H_, W0hT);
    transb  <<<dim3(2 * H_ / 32, G4_ / 32), 256, 0, stream>>>(W1, 0, 2 * H_, W1T);

    // chunked input projection + persistent recurrence segments
    // (4th segment runs t in [96,129): drain iteration folded in)
    for (int c = 0; c < T_ / CH_; ++c) {
        decomp_chunk<<<(MC_ * NA_ / 4 + 255) / 256, 256, 0, stream>>>(X, c, Xc_hi, Xc_lo);
        gemm_bf16x3<<<(MC_ / 128) * (G4_ / 128), 256, 0, stream>>>(
            Xc_hi, Xc_lo, W0xT_hi, W0xT_lo, Z0c, MC_, G4_, NA_);
        const int tEnd = (c == T_ / CH_ - 1) ? (T_ + 1) : (c * CH_ + CH_);
        lstm_persist<<<NWGP_, 512, 0, stream>>>(c * CH_, tEnd, Z0c,
                                                W0hT, W1T, b0, b1, h0blk, h1blk,
                                                c0, c1, hsblk, slots, flag);
    }

    // output head
    out_softmax<<<BT_ / 4, 256, 0, stream>>>(hsblk, Wout, bout, out);
}

// Round 20
// 3982.076 us; speedup vs baseline: 1.1387x; 1.1387x over previous
//
#include <hip/hip_runtime.h>
#include <stdint.h>

// ---------------------------------------------------------------------------
// 2-layer LSTM (B=64,T=128,NA=2048,H=1024) + softmax head, bf16 MFMA.
//   per 32-step chunk: Z0c = Xc @ W0x (bf16x3 MFMA GEMM) then ONE persistent
//   segment running 32 pipelined iterations (L0(t) || L1(t-1)).
// R20 = R18 kernels byte-identical (best clean run, 3995us, no spill) +
//   host-side-only drain-fold: last segment runs t in [96,129], eliminating
//   the separate drain launch + its weight restage. (R19's kernel pipelining
//   caused a spill regression — reverted.)
//   Structure: 256 WGs x 512 thr, 16 units x 32 batches per WG (24 MB/iter
//   broadcast), W single-bf16 in VGPRs (wh[4][8]), blocked h/hs layouts,
//   sc0sc1 read-through A-loads + vmcnt(0) per pass, light 2-hop barrier,
//   sc1 cross-WG stores, c-state in VGPRs across segments.
// ---------------------------------------------------------------------------

typedef __attribute__((ext_vector_type(4))) float f32x4;
typedef __attribute__((ext_vector_type(8))) short short8x;
typedef unsigned short ushort_t;

constexpr int B_  = 64;
constexpr int T_  = 128;
constexpr int NA_ = 2048;
constexpr int H_  = 1024;
constexpr int C_  = 10;
constexpr int BT_ = B_ * T_;     // 8192
constexpr int G4_ = 4 * H_;      // 4096
constexpr int HB_ = B_ * H_;     // 65536 ushorts per parity (blocked 128x64x8)
constexpr int CH_ = 32;          // timesteps per chunk
constexpr int MC_ = B_ * CH_;    // 2048 rows per chunk
constexpr int NWGP_ = 256;       // persistent grid, 1 WG/CU

__device__ __forceinline__ ushort_t f2bf(float x) {
    uint32_t u = __float_as_uint(x);
    uint32_t r = (u + 0x7FFFu + ((u >> 16) & 1u)) >> 16;   // RNE
    return (ushort_t)r;
}
__device__ __forceinline__ float bf2f(ushort_t h) {
    return __uint_as_float((uint32_t)h << 16);
}
__device__ __forceinline__ float sigmf(float x) { return 1.0f / (1.0f + expf(-x)); }

__device__ __forceinline__ void st_u32(void* p, uint32_t v) {
    __hip_atomic_store((uint32_t*)p, v, __ATOMIC_RELAXED, __HIP_MEMORY_SCOPE_AGENT);
}

// Coalesced read-through 16B load (reads coherence point; needs vmcnt fence)
#define AH_ISSUE(dst, ptr) \
    asm volatile("global_load_dwordx4 %0, %1, off sc0 sc1" : "=v"(dst) : "v"(ptr))

#define GLOAD_LDS(gp, lp) \
    __builtin_amdgcn_global_load_lds((const __attribute__((address_space(1))) uint32_t*)(gp), \
                                     (__attribute__((address_space(3))) uint32_t*)(lp), 16, 0, 0)

// ---------------------------------------------------------------------------
// X chunk c -> (hi, lo) decompose with row remap m' = b*CH + (t & 31)
// ---------------------------------------------------------------------------
__global__ void decomp_chunk(const float* __restrict__ X, int c,
                             ushort_t* __restrict__ Hi, ushort_t* __restrict__ Lo) {
    const int i = blockIdx.x * blockDim.x + threadIdx.x;
    if (i >= MC_ * NA_ / 4) return;
    const int mp = i >> 9;
    const int kq = i & 511;
    const int b = mp >> 5, j = mp & 31;
    const size_t src = ((size_t)(b * T_ + c * CH_ + j)) * NA_ + (size_t)kq * 4;
    float4 v = *(const float4*)(X + src);
    ushort4 hi, lo;
    hi.x = f2bf(v.x); lo.x = f2bf(v.x - bf2f(hi.x));
    hi.y = f2bf(v.y); lo.y = f2bf(v.y - bf2f(hi.y));
    hi.z = f2bf(v.z); lo.z = f2bf(v.z - bf2f(hi.z));
    hi.w = f2bf(v.w); lo.w = f2bf(v.w - bf2f(hi.w));
    ((ushort4*)Hi)[i] = hi;
    ((ushort4*)Lo)[i] = lo;
}

// ---------------------------------------------------------------------------
// W -> T{hi,lo}[n][k] bf16 transpose (input-projection GEMM operands)
// ---------------------------------------------------------------------------
__global__ void transdec(const float* __restrict__ W, int rowOff, int Klen,
                         ushort_t* __restrict__ Thi, ushort_t* __restrict__ Tlo) {
    __shared__ float tile[32][33];
    const int k0 = blockIdx.x * 32, n0 = blockIdx.y * 32;
    const int tx = threadIdx.x & 31, ty = threadIdx.x >> 5;
#pragma unroll
    for (int i = 0; i < 32; i += 8)
        tile[ty + i][tx] = W[(size_t)(rowOff + k0 + ty + i) * G4_ + n0 + tx];
    __syncthreads();
#pragma unroll
    for (int i = 0; i < 32; i += 8) {
        float v = tile[tx][ty + i];
        int n = n0 + ty + i;
        int kk = k0 + tx;
        ushort_t hi = f2bf(v);
        Thi[(size_t)n * Klen + kk] = hi;
        Tlo[(size_t)n * Klen + kk] = f2bf(v - bf2f(hi));
    }
}

// ---------------------------------------------------------------------------
// W -> T[n][k] bf16 transpose, hi only (recurrent weights, single-bf16)
// ---------------------------------------------------------------------------
__global__ void transb(const float* __restrict__ W, int rowOff, int Klen,
                       ushort_t* __restrict__ Tq) {
    __shared__ float tile[32][33];
    const int k0 = blockIdx.x * 32, n0 = blockIdx.y * 32;
    const int tx = threadIdx.x & 31, ty = threadIdx.x >> 5;
#pragma unroll
    for (int i = 0; i < 32; i += 8)
        tile[ty + i][tx] = W[(size_t)(rowOff + k0 + ty + i) * G4_ + n0 + tx];
    __syncthreads();
#pragma unroll
    for (int i = 0; i < 32; i += 8) {
        float v = tile[tx][ty + i];
        int n = n0 + ty + i;
        Tq[(size_t)n * Klen + k0 + tx] = f2bf(v);
    }
}

// ---------------------------------------------------------------------------
// C[M][N] (fp32) = A[M][K] x Bt[N][K]^T  bf16x3; m97-style 128x128 tile.
// ---------------------------------------------------------------------------
__global__ __launch_bounds__(256, 2)
void gemm_bf16x3(const ushort_t* __restrict__ Ahi, const ushort_t* __restrict__ Alo,
                 const ushort_t* __restrict__ Bhi, const ushort_t* __restrict__ Blo,
                 float* __restrict__ C, int M, int N, int K) {
    __shared__ ushort_t sA[2][128 * 64];
    __shared__ ushort_t sB[2][128 * 64];

    const int tid  = threadIdx.x;
    const int lane = tid & 63;
    const int wv   = tid >> 6;
    const int wr   = wv >> 1, wc = wv & 1;
    const int tiles_n = N >> 7;
    int id = blockIdx.x;
    const int q8 = gridDim.x >> 3;
    id = (id & 7) * q8 + (id >> 3);
    const int tm = (id / tiles_n) * 128, tn = (id % tiles_n) * 128;

    f32x4 acc[4][4] = {};

    for (int k0 = 0; k0 < K; k0 += 64) {
#pragma unroll
        for (int rd = 0; rd < 4; ++rd) {
            const int off = rd * 4096 + tid * 16;
            const int r   = off >> 7;
            const int kc  = ((off >> 4) & 7) ^ (r & 7);
            const size_t aoff = (size_t)(tm + r) * K + k0 + kc * 8;
            const size_t boff = (size_t)(tn + r) * K + k0 + kc * 8;
            const int dst = (rd * 4096 + wv * 1024) >> 1;
            GLOAD_LDS(Ahi + aoff, (ushort_t*)sA[0] + dst);
            GLOAD_LDS(Alo + aoff, (ushort_t*)sA[1] + dst);
            GLOAD_LDS(Bhi + boff, (ushort_t*)sB[0] + dst);
            GLOAD_LDS(Blo + boff, (ushort_t*)sB[1] + dst);
        }
        __syncthreads();
#pragma unroll
        for (int ks = 0; ks < 2; ++ks) {
            short8x ah[4], al[4], bh[4], bl[4];
#pragma unroll
            for (int i = 0; i < 4; ++i) {
                const int kc = ks * 4 + (lane >> 4);
                const int ra = wr * 64 + i * 16 + (lane & 15);
                const int ea = ra * 64 + ((kc ^ (ra & 7)) * 8);
                ah[i] = *(const short8x*)(&sA[0][ea]);
                al[i] = *(const short8x*)(&sA[1][ea]);
                const int rb = wc * 64 + i * 16 + (lane & 15);
                const int eb = rb * 64 + ((kc ^ (rb & 7)) * 8);
                bh[i] = *(const short8x*)(&sB[0][eb]);
                bl[i] = *(const short8x*)(&sB[1][eb]);
            }
#pragma unroll
            for (int i = 0; i < 4; ++i)
#pragma unroll
                for (int j = 0; j < 4; ++j) {
                    acc[i][j] = __builtin_amdgcn_mfma_f32_16x16x32_bf16(ah[i], bh[j], acc[i][j], 0, 0, 0);
                    acc[i][j] = __builtin_amdgcn_mfma_f32_16x16x32_bf16(ah[i], bl[j], acc[i][j], 0, 0, 0);
                    acc[i][j] = __builtin_amdgcn_mfma_f32_16x16x32_bf16(al[i], bh[j], acc[i][j], 0, 0, 0);
                }
        }
        __syncthreads();
    }
#pragma unroll
    for (int i = 0; i < 4; ++i)
#pragma unroll
        for (int j = 0; j < 4; ++j)
#pragma unroll
            for (int qq = 0; qq < 4; ++qq) {
                const int row = tm + wr * 64 + i * 16 + (lane >> 4) * 4 + qq;
                const int col = tn + wc * 64 + j * 16 + (lane & 15);
                C[(size_t)row * N + col] = acc[i][j][qq];
            }
}

// ---------------------------------------------------------------------------
// Light two-hop grid barrier (probe-verified <2.8us/iter at 256 WGs).
// ---------------------------------------------------------------------------
__device__ __forceinline__ void grid_bar(unsigned* slots, unsigned* flag, unsigned epoch) {
    __syncthreads();   // drains vmcnt: this WG's sc1 stores are globally visible
    if (threadIdx.x == 0)
        __hip_atomic_store(&slots[blockIdx.x], epoch, __ATOMIC_RELAXED, __HIP_MEMORY_SCOPE_AGENT);
    if (blockIdx.x == 0) {
        if (threadIdx.x < NWGP_) {
            unsigned spins = 0;
            while (__hip_atomic_load(&slots[threadIdx.x], __ATOMIC_RELAXED, __HIP_MEMORY_SCOPE_AGENT) < epoch
                   && ++spins < (1u << 20))
                __builtin_amdgcn_s_sleep(4);
        }
        __syncthreads();
        if (threadIdx.x == 0)
            __hip_atomic_store(flag, epoch, __ATOMIC_RELAXED, __HIP_MEMORY_SCOPE_AGENT);
    } else {
        if (threadIdx.x == 0) {
            unsigned spins = 0;
            while (__hip_atomic_load(flag, __ATOMIC_RELAXED, __HIP_MEMORY_SCOPE_AGENT) < epoch
                   && ++spins < (1u << 20))
                __builtin_amdgcn_s_sleep(4);
        }
    }
    __syncthreads();
}

// ---------------------------------------------------------------------------
// Persistent recurrence SEGMENT. 256 WGs x 512 thr (1 WG/CU).
// WG w<128: L0; else L1. lw = w mod 128: uB16 = lw>>1 (16-unit block 0..63),
// mh = lw&1 (batch half: m0 = mh*32). N=64 gate-rows/WG, M=32 batches/WG.
// 8 waves K-split (KS 128/256, NKS 4/8 -> npass 2/4). W in VGPRs wh[4][8].
// h blocked [parity][kblock(128)][batch(64)][8]; A-frag = one 16B read.
// c-state in VGPRs across the segment. LDS = zbuf only.
// ---------------------------------------------------------------------------
__global__ __launch_bounds__(512, 1)
void lstm_persist(int t0, int t1,
                  const float* __restrict__ Z0c,
                  const ushort_t* __restrict__ W0hT, const ushort_t* __restrict__ W1T,
                  const float* __restrict__ b0, const float* __restrict__ b1,
                  ushort_t* __restrict__ h0blk, ushort_t* __restrict__ h1blk,
                  float* __restrict__ c0, float* __restrict__ c1,
                  ushort_t* __restrict__ hsblk, unsigned* slots, unsigned* flag) {
    const int w = blockIdx.x;
    const bool isL0 = (w < 128);
    const int lw = isL0 ? w : (w - 128);
    const int uB16 = lw >> 1;          // 16-unit block 0..63
    const int mh   = lw & 1;           // batch half
    const int u0 = uB16 * 16;
    const int m0 = mh * 32;
    const int tid = threadIdx.x, lane = tid & 63, kv = tid >> 6;
    const int K   = isL0 ? H_ : 2 * H_;
    const int KS  = K >> 3;            // 128 / 256
    const int NKS = KS >> 5;           // 4 / 8
    const int kbase = kv * KS;

    __shared__ float zbuf[32][65];     // 8.3 KB — only LDS use

    // --- startup: weights (single bf16) -> VGPRs, fragment layout ---
    // gate-row n (0..63): gate g = n>>4, unit = n&15; grow = g*H_ + u0 + unit
    const ushort_t* Whi = isL0 ? W0hT : W1T;
    short8x wh[4][8] = {};
#pragma unroll
    for (int jn = 0; jn < 4; ++jn)
#pragma unroll
        for (int s = 0; s < 8; ++s)
            if (s < NKS) {
                const int n = jn * 16 + (lane & 15);
                const int grow = (n >> 4) * H_ + u0 + (n & 15);
                wh[jn][s] = *(const short8x*)(Whi + (size_t)grow * K + kbase + s * 32 + (lane >> 4) * 8);
            }

    // epilogue mapping: threads 0..255, each (local batch ml, unit pair jp,jp+1)
    const bool epi = (tid < 256);
    const int ml = tid >> 3;           // 0..31
    const int em = m0 + ml;            // global batch
    const int jp = (tid & 7) * 2;      // 0..14
    const int eu = u0 + jp;
    const float* bias = isL0 ? b0 : b1;
    const float bi0 = epi ? bias[eu]            : 0.f, bi1 = epi ? bias[eu + 1]            : 0.f;
    const float bj0 = epi ? bias[H_ + eu]       : 0.f, bj1 = epi ? bias[H_ + eu + 1]       : 0.f;
    const float bf0 = epi ? bias[2 * H_ + eu]   : 0.f, bf1 = epi ? bias[2 * H_ + eu + 1]   : 0.f;
    const float bo0 = epi ? bias[3 * H_ + eu]   : 0.f, bo1 = epi ? bias[3 * H_ + eu + 1]   : 0.f;
    const int zm = tid >> 4, zj = (tid & 15) * 4;   // zbuf zero map (512 thr x 4)

    // c-state resident in VGPRs for the segment
    float cr0 = 0.f, cr1 = 0.f;
    float* cptr = (isL0 ? c0 : c1) + (size_t)em * H_ + eu;
    if (epi) { float2 cv = *(const float2*)cptr; cr0 = cv.x; cr1 = cv.y; }

    for (int t = t0; t < t1; ++t) {
        const bool active = isL0 ? (t < T_) : (t >= 1);
        if (active) {
            const int tt = isL0 ? t : t - 1;
            const ushort_t* h0prev = h0blk + ((tt + 1) & 1) * HB_;
            const ushort_t* h0cur  = h0blk + (tt & 1) * HB_;
            const ushort_t* h1prev = h1blk + ((tt + 1) & 1) * HB_;

            // zero gate-exchange cells (4 per thread: 512x4 = 32x64)
            zbuf[zm][zj] = 0.f; zbuf[zm][zj + 1] = 0.f;
            zbuf[zm][zj + 2] = 0.f; zbuf[zm][zj + 3] = 0.f;
            __syncthreads();

            // Z0c prefetch (plain cached)
            float2 zx0 = {0.f, 0.f}, zx1 = {0.f, 0.f}, zx2 = {0.f, 0.f}, zx3 = {0.f, 0.f};
            if (isL0 && epi) {
                const float* zr = Z0c + ((size_t)em * CH_ + (tt & (CH_ - 1))) * G4_;
                zx0 = *(const float2*)(zr + eu);
                zx1 = *(const float2*)(zr + H_ + eu);
                zx2 = *(const float2*)(zr + 2 * H_ + eu);
                zx3 = *(const float2*)(zr + 3 * H_ + eu);
            }

            f32x4 acc[2][4] = {};
            short8x ah[2][2];                 // 4 x 16B live = 16 VGPRs
            const int npass = NKS >> 1;       // 2 for L0, 4 for L1
#pragma unroll
            for (int pp = 0; pp < 4; ++pp)
                if (pp < npass) {
                    // issue 4 A-loads (2 k-steps x 2 M-frags)
#pragma unroll
                    for (int s2 = 0; s2 < 2; ++s2) {
                        const int s = pp * 2 + s2;
                        const int kg = kbase + s * 32;
                        const ushort_t* base;
                        int kk;
                        if (isL0)           { base = h0prev; kk = kg; }
                        else if (kg < 1024) { base = h0cur;  kk = kg; }
                        else                { base = h1prev; kk = kg - 1024; }
                        const int kaa = kk + (lane >> 4) * 8;
#pragma unroll
                        for (int i = 0; i < 2; ++i) {
                            const int batch = m0 + i * 16 + (lane & 15);
                            AH_ISSUE(ah[s2][i],
                                     base + (size_t)(kaa >> 3) * 512 + (size_t)batch * 8);
                        }
                    }
                    asm volatile("s_waitcnt vmcnt(0)" ::: "memory");
                    __builtin_amdgcn_sched_barrier(0);
#pragma unroll
                    for (int s2 = 0; s2 < 2; ++s2) {
                        const int s = pp * 2 + s2;
#pragma unroll
                        for (int i = 0; i < 2; ++i) {
                            acc[i][0] = __builtin_amdgcn_mfma_f32_16x16x32_bf16(ah[s2][i], wh[0][s], acc[i][0], 0, 0, 0);
                            acc[i][1] = __builtin_amdgcn_mfma_f32_16x16x32_bf16(ah[s2][i], wh[1][s], acc[i][1], 0, 0, 0);
                            acc[i][2] = __builtin_amdgcn_mfma_f32_16x16x32_bf16(ah[s2][i], wh[2][s], acc[i][2], 0, 0, 0);
                            acc[i][3] = __builtin_amdgcn_mfma_f32_16x16x32_bf16(ah[s2][i], wh[3][s], acc[i][3], 0, 0, 0);
                        }
                    }
                }
            // K-reduction across 8 waves; per-wave rotated order
#pragma unroll
            for (int i2 = 0; i2 < 2; ++i2) {
                const int i = (i2 + (kv & 1)) & 1;
#pragma unroll
                for (int jn2 = 0; jn2 < 4; ++jn2) {
                    const int jn = (jn2 + (kv >> 1)) & 3;
#pragma unroll
                    for (int qq = 0; qq < 4; ++qq) {
                        const int m = i * 16 + (lane >> 4) * 4 + qq;     // local batch
                        const int n = jn * 16 + (lane & 15);             // gate-row
                        atomicAdd(&zbuf[m][n], acc[i][jn][qq]);
                    }
                }
            }
            __syncthreads();

            // epilogue: threads 0..255; gate-row n = g*16 + unit
            if (epi) {
                const float zi0 = zbuf[ml][jp]          + bi0 + zx0.x;
                const float zi1 = zbuf[ml][jp + 1]      + bi1 + zx0.y;
                const float zj0 = zbuf[ml][16 + jp]     + bj0 + zx1.x;
                const float zj1 = zbuf[ml][16 + jp + 1] + bj1 + zx1.y;
                const float zf0 = zbuf[ml][32 + jp]     + bf0 + zx2.x;
                const float zf1 = zbuf[ml][32 + jp + 1] + bf1 + zx2.y;
                const float zo0 = zbuf[ml][48 + jp]     + bo0 + zx3.x;
                const float zo1 = zbuf[ml][48 + jp + 1] + bo1 + zx3.y;
                const float cn0 = cr0 * sigmf(zf0 + 1.0f) + sigmf(zi0) * tanhf(zj0);
                const float cn1 = cr1 * sigmf(zf1 + 1.0f) + sigmf(zi1) * tanhf(zj1);
                cr0 = cn0; cr1 = cn1;
                const float hv0 = tanhf(cn0) * sigmf(zo0);
                const float hv1 = tanhf(cn1) * sigmf(zo1);
                const uint32_t hhp = (uint32_t)f2bf(hv0) | ((uint32_t)f2bf(hv1) << 16);
                const int kb = uB16 * 2 + (jp >> 3);       // 8-unit block
                const size_t hoff = ((size_t)kb * 64 + em) * 8 + (jp & 7);
                if (isL0) {
                    st_u32(h0blk + (tt & 1) * HB_ + hoff, hhp);
                } else {
                    st_u32(h1blk + (tt & 1) * HB_ + hoff, hhp);
                    st_u32(hsblk + (((size_t)tt * 128 + kb) * 64 + em) * 8 + (jp & 7), hhp);
                }
            }
        }
        if (t < T_) grid_bar(slots, flag, (unsigned)(t + 1));
    }

    // c-state back to global (plain; flushed at end-of-kernel)
    if (epi) { float2 cv; cv.x = cr0; cv.y = cr1; *(float2*)cptr = cv; }
}

// ---------------------------------------------------------------------------
// logits = hs @ Wout + bout; softmax over C=10. One wave per (b,t) row.
// hs blocked: hs[((t*128 + (k>>3))*512) + b*8 + (k&7)].
// ---------------------------------------------------------------------------
__global__ __launch_bounds__(256)
void out_softmax(const ushort_t* __restrict__ hs, const float* __restrict__ Wout,
                 const float* __restrict__ bout, float* __restrict__ out) {
    const int row  = blockIdx.x * 4 + (threadIdx.x >> 6);
    const int lane = threadIdx.x & 63;
    const int b = row >> 7, t = row & (T_ - 1);
    float s[C_];
#pragma unroll
    for (int c = 0; c < C_; ++c) s[c] = 0.f;
    for (int k = lane; k < H_; k += 64) {
        const float hv = bf2f(hs[((size_t)t * 128 + (k >> 3)) * 512 + (size_t)b * 8 + (k & 7)]);
        const float* w = Wout + k * C_;
#pragma unroll
        for (int c = 0; c < C_; ++c) s[c] += hv * w[c];
    }
#pragma unroll
    for (int c = 0; c < C_; ++c) {
#pragma unroll
        for (int d = 32; d > 0; d >>= 1) s[c] += __shfl_xor(s[c], d);
        s[c] += bout[c];
    }
    float mx = s[0];
#pragma unroll
    for (int c = 1; c < C_; ++c) mx = fmaxf(mx, s[c]);
    float sum = 0.f;
#pragma unroll
    for (int c = 0; c < C_; ++c) { s[c] = expf(s[c] - mx); sum += s[c]; }
    const float inv = 1.0f / sum;
    if (lane < C_) {
        float pv = 0.f;
#pragma unroll
        for (int c = 0; c < C_; ++c)
            if (lane == c) pv = s[c] * inv;
        out[(size_t)row * C_ + lane] = pv;
    }
}

// ---------------------------------------------------------------------------
extern "C" void kernel_launch(void* const* d_in, const int* in_sizes, int n_in,
                              void* d_out, int out_size, void* d_ws, size_t ws_size,
                              hipStream_t stream) {
    const float* X    = (const float*)d_in[0];
    const float* W0   = (const float*)d_in[1];
    const float* b0   = (const float*)d_in[2];
    const float* W1   = (const float*)d_in[3];
    const float* b1   = (const float*)d_in[4];
    const float* Wout = (const float*)d_in[5];
    const float* bout = (const float*)d_in[6];
    float* out = (float*)d_out;

    // ws layout (~121 MB)
    char* p = (char*)d_ws;
    size_t off = 0;
    auto take = [&](size_t bytes) { char* r = p + off; off += bytes; return r; };
    ushort_t* W0xT_hi = (ushort_t*)take((size_t)G4_ * NA_ * 2);     // 16 MB
    ushort_t* W0xT_lo = (ushort_t*)take((size_t)G4_ * NA_ * 2);     // 16 MB
    ushort_t* W0hT    = (ushort_t*)take((size_t)G4_ * H_ * 2);      // 8 MB
    ushort_t* W1T     = (ushort_t*)take((size_t)G4_ * 2 * H_ * 2);  // 16 MB
    ushort_t* Xc_hi   = (ushort_t*)take((size_t)MC_ * NA_ * 2);     // 8 MB
    ushort_t* Xc_lo   = (ushort_t*)take((size_t)MC_ * NA_ * 2);     // 8 MB
    float*    Z0c     = (float*)take((size_t)MC_ * G4_ * 4);        // 32 MB
    ushort_t* hsblk   = (ushort_t*)take((size_t)BT_ * H_ * 2);      // 16 MB
    float*    c0      = (float*)take((size_t)B_ * H_ * 4);
    float*    c1      = (float*)take((size_t)B_ * H_ * 4);
    ushort_t* h0blk   = (ushort_t*)take((size_t)2 * HB_ * 2);
    ushort_t* h1blk   = (ushort_t*)take((size_t)2 * HB_ * 2);
    unsigned* bar     = (unsigned*)take(2048);
    if (ws_size < off) return;

    unsigned* slots = bar;          // 256 x u32 per-WG arrival slots
    unsigned* flag  = bar + 256;    // release flag

    // zero-state init (parity-1 regions are the t=-1 reads); barrier = 0
    (void)hipMemsetAsync(c0, 0, (size_t)B_ * H_ * 4, stream);
    (void)hipMemsetAsync(c1, 0, (size_t)B_ * H_ * 4, stream);
    (void)hipMemsetAsync(h0blk + HB_, 0, (size_t)HB_ * 2, stream);
    (void)hipMemsetAsync(h1blk + HB_, 0, (size_t)HB_ * 2, stream);
    (void)hipMemsetAsync(bar, 0, 2048, stream);

    // weight prep
    transdec<<<dim3(NA_ / 32, G4_ / 32), 256, 0, stream>>>(W0, 0, NA_, W0xT_hi, W0xT_lo);
    transb  <<<dim3(H_ / 32, G4_ / 32), 256, 0, stream>>>(W0, NA_, H_, W0hT);
    transb  <<<dim3(2 * H_ / 32, G4_ / 32), 256, 0, stream>>>(W1, 0, 2 * H_, W1T);

    // chunked input projection + persistent recurrence segments
    // (4th segment runs t in [96,129): drain iteration folded in, host-side only)
    for (int c = 0; c < T_ / CH_; ++c) {
        decomp_chunk<<<(MC_ * NA_ / 4 + 255) / 256, 256, 0, stream>>>(X, c, Xc_hi, Xc_lo);
        gemm_bf16x3<<<(MC_ / 128) * (G4_ / 128), 256, 0, stream>>>(
            Xc_hi, Xc_lo, W0xT_hi, W0xT_lo, Z0c, MC_, G4_, NA_);
        const int tEnd = (c == T_ / CH_ - 1) ? (T_ + 1) : (c * CH_ + CH_);
        lstm_persist<<<NWGP_, 512, 0, stream>>>(c * CH_, tEnd, Z0c,
                                                W0hT, W1T, b0, b1, h0blk, h1blk,
                                                c0, c1, hsblk, slots, flag);
    }

    // output head
    out_softmax<<<BT_ / 4, 256, 0, stream>>>(hsblk, Wout, bout, out);
}